// Round 12
// baseline (437.379 us; speedup 1.0000x reference)
//
#include <hip/hip_runtime.h>
#include <stdint.h>

typedef int int32x4  __attribute__((ext_vector_type(4)));
typedef int int32x16 __attribute__((ext_vector_type(16)));

#define IN_F   4096
#define OUT_F  4096
#define ROWS   8192   /* 4 * 2048 */

#define BM 128
#define BN 128
#define BK 64
#define NT (IN_F / BK)           /* 64 K-tiles */
#define ABUF 8192                /* A tile: 128x64 i8 = 8 KB */
#define LDS_TOTAL (4 * ABUF)     /* quad buffer = 32 KB -> 3 blocks/CU fit */

// async global->LDS, 16B per lane; LDS dest must be lane-contiguous (m104/m108)
#define GLOAD_LDS16(g, l)                                                      \
  __builtin_amdgcn_global_load_lds(                                            \
      (const __attribute__((address_space(1))) void*)(g),                      \
      (__attribute__((address_space(3))) void*)(l), 16, 0, 0)

__device__ __forceinline__ int pack4i(int a, int b, int c, int d) {
  return (a & 0xff) | ((b & 0xff) << 8) | ((c & 0xff) << 16) | (d << 24);
}

// ---- cvt into MFMA-native packed layout (flatmm): 16B chunk (eb, kb, l) at
// (eb*128 + kb)*1024 + l*16; lane l of a fragment holds row eb*32 + (l&31),
// k bytes kb*32 + (l>>5)*16.  Thread t handles source block (base>>5)+(t&7),
// row r = t>>3: reads 8 x int4 (32 k-values of row eb*32+r), writes chunks
// l=r and l=r+32.  r10 BUG FIX: row stride is 1024 vec4s (4096 elems / 4),
// NOT 256 — r9/r10 read wrong rows (absmax 255).  R8's cvt used 1024.
#define CVT_BLOCKS 2048
#define CVT_NA 1048576   /* 8192*4096/32 */
#define CVT_NTOT 1572864 /* + 4096*4096/32 */
__global__ void __launch_bounds__(256) cvt_kernel(const int4* __restrict__ x,
                                                  const float4* __restrict__ w,
                                                  int4* __restrict__ oa,
                                                  int4* __restrict__ ob) {
  const int t = threadIdx.x;
  for (size_t base = (size_t)blockIdx.x * 256; base < CVT_NTOT;
       base += (size_t)CVT_BLOCKS * 256) {
    if (base < CVT_NA) {                 // region boundary is block-uniform
      const int block = (int)(base >> 5) + (t & 7);
      const int r = t >> 3;
      const int m = (block >> 7) * 32 + r, kb = block & 127;
      const int4* src = x + (size_t)m * 1024 + kb * 8;   // 1024 int4 per row
      int p[8];
#pragma unroll
      for (int j = 0; j < 8; ++j) {
        int4 a = src[j];
        p[j] = pack4i(a.x, a.y, a.z, a.w);
      }
      oa[(size_t)block * 64 + r]      = make_int4(p[0], p[1], p[2], p[3]);
      oa[(size_t)block * 64 + r + 32] = make_int4(p[4], p[5], p[6], p[7]);
    } else {
      const size_t b2 = base - CVT_NA;
      const int block = (int)(b2 >> 5) + (t & 7);
      const int r = t >> 3;
      const int n = (block >> 7) * 32 + r, kb = block & 127;
      const float4* src = w + (size_t)n * 1024 + kb * 8; // 1024 float4 per row
      int p[8];
#pragma unroll
      for (int j = 0; j < 8; ++j) {
        float4 a = src[j];
        p[j] = pack4i(__float2int_rn(a.x), __float2int_rn(a.y),
                      __float2int_rn(a.z), __float2int_rn(a.w));
      }
      ob[(size_t)block * 64 + r]      = make_int4(p[0], p[1], p[2], p[3]);
      ob[(size_t)block * 64 + r + 32] = make_int4(p[4], p[5], p[6], p[7]);
    }
  }
}

// ---- i8 MFMA GEMM on packed operands ---------------------------------------
// r0-r8 post-mortem: EVERY schedule at 1 block/CU lands at ~160us / 37-41%
// MfmaUtil -- the invariant is barrier lockstep: all resident waves belong to
// ONE block, so every barrier converts LDS/VMEM queue skew (~700 cyc) into
// CU-wide idle, and nothing fills it (m114 overlap needs independent blocks).
// acc=128 VGPR made a 2nd block impossible.  THIS version: 128x128 block,
// 256 thr (2x2 waves), wave-tile 64x64 -> acc=64; launch_bounds(256,3) ->
// 3 blocks/CU desynced.  LDS 32KB/block (3x fit in 160KB).
// A: LDS-staged (packed-linear DMA, contiguous-1024B frag reads, 0 conflicts);
// B: global->reg ping-pong (4 x dwordx4/tile, contiguous 1024B, L2-resident
// via bn-major XCD map: 4 panels x 512KB = 2MB/XCD).  Counted vmcnt(2) gate.
// Fragment maps (harness-verified): A/B: m|n = lane&31, k-bytes (lane>>5)*16;
// C/D: col = lane&31, row = (reg&3) + 8*(reg>>2) + 4*(lane>>5).
__global__ void __launch_bounds__(256, 3) gemm_i8_kernel(
    const int8_t* __restrict__ A8p, const int8_t* __restrict__ B8p,
    const float* __restrict__ bias, const float* __restrict__ alpha_p,
    int* __restrict__ out) {
  extern __shared__ int8_t lds[];

  const int t    = threadIdx.x;
  const int wave = t >> 6;
  const int lane = t & 63;
  const int l31  = lane & 31;
  const int hi   = lane >> 5;
  const int wm   = wave >> 1;   // 0..1
  const int wn   = wave & 1;    // 0..1

  // XCD-aware bijective swizzle: 2048 blocks % 8 == 0; bn-major per XCD.
  const int flat = blockIdx.y * gridDim.x + blockIdx.x;  // 0..2047
  const int wid  = (flat & 7) * 256 + (flat >> 3);
  const int bn   = wid >> 6;    // 0..31
  const int bm   = wid & 63;    // 0..63

  // A DMA: tile = 512 chunks (eb 4 x kb 2 x l 64); thread t, round j:
  // c = j*256 + t -> eb = j*2 + (t>>7), kb = (t>>6)&1, l = t&63.
  const int ebT = t >> 7, kbT = (t >> 6) & 1, lT = t & 63;
  const size_t aOff0 = ((size_t)(bm * 4 + ebT) * 128 + kbT) * 1024 + lT * 16;
  const size_t aOff1 = ((size_t)(bm * 4 + ebT + 2) * 128 + kbT) * 1024 + lT * 16;
  const int ldsT = t * 16;

  // B direct: frag (ni, ks) of tile T at ((bn*4 + wn*2 + ni)*128 + T*2+ks)*1024
  const int8_t* bPtr = B8p + (size_t)(bn * 4 + wn * 2) * 131072 + (size_t)lane * 16;

  // A frag read: buf + ((wm*2+mi)*2 + ks)*1024 + lane*16 (contiguous 1024B)
  const int aLds = wm * 4096 + lane * 16;

  int32x16 acc[2][2] = {};
  int32x4 af[2][2];
  int32x4 Bc00, Bc01, Bc10, Bc11, Bn00, Bn01, Bn10, Bn11;

#define ISSUE_A(TILE)                                                          \
  do {                                                                         \
    int8_t* _b = lds + ((TILE) & 3) * ABUF;                                    \
    GLOAD_LDS16(A8p + aOff0 + (size_t)(TILE) * 2048, _b + ldsT);               \
    GLOAD_LDS16(A8p + aOff1 + (size_t)(TILE) * 2048, _b + 4096 + ldsT);        \
  } while (0)

#define LOAD_B(TILE, B00, B01, B10, B11)                                       \
  do {                                                                         \
    const int8_t* _p = bPtr + (size_t)(TILE) * 2048;                           \
    B00 = *(const int32x4*)(_p);                                               \
    B01 = *(const int32x4*)(_p + 1024);                                        \
    B10 = *(const int32x4*)(_p + 131072);                                      \
    B11 = *(const int32x4*)(_p + 131072 + 1024);                               \
  } while (0)

#define READ_A(TILE)                                                           \
  do {                                                                         \
    const int8_t* _a = lds + ((TILE) & 3) * ABUF + aLds;                       \
    _Pragma("unroll") for (int mi = 0; mi < 2; ++mi) {                         \
      af[mi][0] = *(const int32x4*)(_a + mi * 2048);                           \
      af[mi][1] = *(const int32x4*)(_a + mi * 2048 + 1024);                    \
    }                                                                          \
  } while (0)

#define MFMA8(B00, B01, B10, B11)                                              \
  do {                                                                         \
    __builtin_amdgcn_s_setprio(1);                                             \
    acc[0][0] = __builtin_amdgcn_mfma_i32_32x32x32_i8(af[0][0], B00,           \
                                                      acc[0][0], 0, 0, 0);     \
    acc[0][1] = __builtin_amdgcn_mfma_i32_32x32x32_i8(af[0][0], B10,           \
                                                      acc[0][1], 0, 0, 0);     \
    acc[1][0] = __builtin_amdgcn_mfma_i32_32x32x32_i8(af[1][0], B00,           \
                                                      acc[1][0], 0, 0, 0);     \
    acc[1][1] = __builtin_amdgcn_mfma_i32_32x32x32_i8(af[1][0], B10,           \
                                                      acc[1][1], 0, 0, 0);     \
    acc[0][0] = __builtin_amdgcn_mfma_i32_32x32x32_i8(af[0][1], B01,           \
                                                      acc[0][0], 0, 0, 0);     \
    acc[0][1] = __builtin_amdgcn_mfma_i32_32x32x32_i8(af[0][1], B11,           \
                                                      acc[0][1], 0, 0, 0);     \
    acc[1][0] = __builtin_amdgcn_mfma_i32_32x32x32_i8(af[1][1], B01,           \
                                                      acc[1][0], 0, 0, 0);     \
    acc[1][1] = __builtin_amdgcn_mfma_i32_32x32x32_i8(af[1][1], B11,           \
                                                      acc[1][1], 0, 0, 0);     \
    __builtin_amdgcn_s_setprio(0);                                             \
  } while (0)

// gate: completes A(t+1)+B(t+1) (6 oldest), leaves A(t+2)x2 in flight.
#define GATE2                                                                  \
  do {                                                                         \
    asm volatile("s_waitcnt vmcnt(2)" ::: "memory");                           \
    __builtin_amdgcn_s_barrier();                                              \
  } while (0)

  // prologue: queue [A0(2), B0(4), A1(2)] -> vmcnt(2) completes A0,B0
  ISSUE_A(0);
  LOAD_B(0, Bc00, Bc01, Bc10, Bc11);
  ISSUE_A(1);
  GATE2;

  // steady state, unroll-2 for static B ping-pong (rule 20).  Invariant at
  // half-iter top: outstanding = A(tt+1)x2; A(tt) in LDS; B(tt) in use-set.
  for (int tt = 0; tt < NT - 2; tt += 2) {
    LOAD_B(tt + 1, Bn00, Bn01, Bn10, Bn11);
    ISSUE_A(tt + 2);
    READ_A(tt);
    MFMA8(Bc00, Bc01, Bc10, Bc11);
    GATE2;

    LOAD_B(tt + 2, Bc00, Bc01, Bc10, Bc11);
    ISSUE_A(tt + 3);
    READ_A(tt + 1);
    MFMA8(Bn00, Bn01, Bn10, Bn11);
    GATE2;
  }
  // tail: tiles NT-2 (Bc loaded), NT-1; A(NT-2),A(NT-1) already issued
  LOAD_B(NT - 1, Bn00, Bn01, Bn10, Bn11);
  READ_A(NT - 2);
  MFMA8(Bc00, Bc01, Bc10, Bc11);
  asm volatile("s_waitcnt vmcnt(0)" ::: "memory");
  __builtin_amdgcn_s_barrier();
  READ_A(NT - 1);
  MFMA8(Bn00, Bn01, Bn10, Bn11);

  // epilogue: C/D col = lane&31, row = (reg&3) + 8*(reg>>2) + 4*hi
  const float alpha = *alpha_p;
#pragma unroll
  for (int mi = 0; mi < 2; ++mi) {
    const int rowt = bm * BM + wm * 64 + mi * 32 + hi * 4;
#pragma unroll
    for (int ni = 0; ni < 2; ++ni) {
      const int col = bn * BN + wn * 64 + ni * 32 + l31;
      const float bv = bias[col];
#pragma unroll
      for (int r = 0; r < 16; ++r) {
        const int row = rowt + (r & 3) + 8 * (r >> 2);
        float v = rintf((float)acc[mi][ni][r] * alpha + bv);
        v = fminf(fmaxf(v, -128.f), 127.f);
        out[(size_t)row * OUT_F + col] = (int)v;
      }
    }
  }
#undef ISSUE_A
#undef LOAD_B
#undef READ_A
#undef MFMA8
#undef GATE2
}

extern "C" void kernel_launch(void* const* d_in, const int* in_sizes, int n_in,
                              void* d_out, int out_size, void* d_ws, size_t ws_size,
                              hipStream_t stream) {
  const int*   x     = (const int*)d_in[0];    // [8192, 4096] int8-valued
  const float* w     = (const float*)d_in[1];  // [4096, 4096] int8-valued
  const float* bias  = (const float*)d_in[2];  // [4096]
  const float* alpha = (const float*)d_in[3];  // scalar
  int* out = (int*)d_out;                      // [8192, 4096] int32 (int8 values)

  int8_t* x8 = (int8_t*)d_ws;                        // 33,554,432 B (packed A)
  int8_t* w8 = x8 + (size_t)ROWS * IN_F;             // 16,777,216 B (packed B)

  static bool attr_done = false;
  if (!attr_done) {
    (void)hipFuncSetAttribute(reinterpret_cast<const void*>(gemm_i8_kernel),
                              hipFuncAttributeMaxDynamicSharedMemorySize,
                              LDS_TOTAL);
    attr_done = true;
  }

  cvt_kernel<<<CVT_BLOCKS, 256, 0, stream>>>((const int4*)x, (const float4*)w,
                                             (int4*)x8, (int4*)w8);

  dim3 grid(OUT_F / BN, ROWS / BM);  // (32, 64) = 2048 blocks
  gemm_i8_kernel<<<grid, 256, LDS_TOTAL, stream>>>(x8, w8, bias, alpha, out);
}